// Round 3
// baseline (1877.604 us; speedup 1.0000x reference)
//
#include <hip/hip_runtime.h>
#include <hip/hip_fp16.h>

// Problem constants
// B=256, L=2048, C=12, LATENT=256, G=768, T_IN=128, T_OUT=12, S=140, STRIDE=4
// M_sim = 140*256 = 35840, M_gi = 128*256 = 32768

typedef __attribute__((ext_vector_type(4))) float f32x4;
typedef __attribute__((ext_vector_type(8))) _Float16 f16x8;

__device__ inline float sigm(float x) {
    x = fminf(fmaxf(x, -30.f), 30.f);
    return 1.f / (1.f + __expf(-x));
}
__device__ inline float tanh_(float x) {
    x = fminf(fmaxf(x, -15.f), 15.f);
    float e = __expf(2.f * x);
    return (e - 1.f) / (e + 1.f);
}

// ---------------- prep: W_ih -> fp16, zero out[0..1] ----------------
__global__ void wprep_kernel(const float* __restrict__ Wih, __half* __restrict__ wh,
                             float* __restrict__ out) {
    int i = blockIdx.x * 256 + threadIdx.x;   // 768*256 = 196608 total
    wh[i] = __float2half(Wih[i]);
    if (i < 2) out[i] = 0.f;
}

// ---------------- conv encoder: enc[t][b][o], t<140, hi/lo fp16 ----------------
__global__ void conv_kernel(const float* __restrict__ X, const float* __restrict__ cw,
                            const float* __restrict__ cb, __half* __restrict__ ehi,
                            __half* __restrict__ elo) {
    __shared__ float wt[48 * 256];   // transposed: wt[cs*256 + o]
    __shared__ float xs[140 * 12];   // X window for this (b, t-chunk)
    int tid = threadIdx.x;
    int tc = blockIdx.x;   // 0..3, 35 t's each
    int b  = blockIdx.y;   // 0..255
    for (int i = tid; i < 48 * 256; i += 256) {
        int o = i / 48, cs = i % 48;
        wt[cs * 256 + o] = cw[i];
    }
    int xbase = (b * 2048 + tc * 140) * 12;
    for (int i = tid; i < 1680; i += 256) xs[i] = X[xbase + i];
    __syncthreads();
    int o = tid;
    float bias = cb[o];
    for (int tl = 0; tl < 35; ++tl) {
        float acc = bias;
        #pragma unroll
        for (int cs = 0; cs < 48; ++cs) {
            int c = cs >> 2, s = cs & 3;
            acc += xs[(tl * 4 + s) * 12 + c] * wt[cs * 256 + o];
        }
        int t = tc * 35 + tl;
        size_t m = (size_t)(t * 256 + b);
        __half h = __float2half(acc);
        ehi[m * 256 + o] = h;
        elo[m * 256 + o] = __float2half(acc - __half2float(h));
    }
}

// ---------------- gi GEMM: gi[m][j] = enc[m]·W_ih[j] + b_ih[j], fp16 out ----------------
__global__ void gi_gemm(const __half* __restrict__ A, const __half* __restrict__ Bw,
                        const float* __restrict__ bias, __half* __restrict__ out) {
    int tid = threadIdx.x;
    int lane = tid & 63, wid = tid >> 6;
    int wm = wid >> 1, wn = wid & 1;
    int mbase = blockIdx.x * 128 + wm * 64;
    int nbase = blockIdx.y * 128 + wn * 64;
    int lr = lane & 15, kg = lane >> 4;
    f32x4 acc[4][4];
    #pragma unroll
    for (int i = 0; i < 4; ++i)
        #pragma unroll
        for (int j = 0; j < 4; ++j)
            #pragma unroll
            for (int e = 0; e < 4; ++e) acc[i][j][e] = 0.f;
    #pragma unroll
    for (int kc = 0; kc < 8; ++kc) {
        int ko = kc * 32 + kg * 8;
        f16x8 a[4], bb[4];
        #pragma unroll
        for (int mi = 0; mi < 4; ++mi)
            a[mi] = *(const f16x8*)(A + (size_t)(mbase + mi * 16 + lr) * 256 + ko);
        #pragma unroll
        for (int ni = 0; ni < 4; ++ni)
            bb[ni] = *(const f16x8*)(Bw + (size_t)(nbase + ni * 16 + lr) * 256 + ko);
        #pragma unroll
        for (int mi = 0; mi < 4; ++mi)
            #pragma unroll
            for (int ni = 0; ni < 4; ++ni)
                acc[mi][ni] = __builtin_amdgcn_mfma_f32_16x16x32_f16(a[mi], bb[ni], acc[mi][ni], 0, 0, 0);
    }
    #pragma unroll
    for (int mi = 0; mi < 4; ++mi)
        #pragma unroll
        for (int ni = 0; ni < 4; ++ni) {
            int j = nbase + ni * 16 + lr;
            float bj = bias[j];
            #pragma unroll
            for (int r = 0; r < 4; ++r) {
                int m = mbase + mi * 16 + kg * 4 + r;
                out[(size_t)m * 768 + j] = __float2half(acc[mi][ni][r] + bj);
            }
        }
}

// ---------------- GRU: 16 blocks x 16 batch rows, W_hh fp16 in registers ----------------
__global__ void __launch_bounds__(256, 1)
gru_kernel(const float* __restrict__ Whh, const float* __restrict__ bhh,
           const __half* __restrict__ gih, float* __restrict__ cc,
           float* __restrict__ out) {
    __shared__ __align__(16) char hb[2][8192];   // h fp16, [b(16)][l(256)], XOR-swizzled
    int tid = threadIdx.x;
    int lane = tid & 63, w = tid >> 6;          // 4 waves; wave owns l-slice [64w, 64w+64)
    int n = lane & 15, kg = lane >> 4;
    int bg0 = blockIdx.x * 16;

    f16x8 Wf[12][8];   // B-frags: nt = gate*4+q -> j = gate*256 + w*64 + q*16 + n
    float bh[12];
    #pragma unroll
    for (int nt = 0; nt < 12; ++nt) {
        int g = nt >> 2, q = nt & 3;
        int j = g * 256 + w * 64 + q * 16 + n;
        bh[nt] = bhh[j];
        #pragma unroll
        for (int kc = 0; kc < 8; ++kc) {
            const float* wp = Whh + (size_t)j * 256 + kc * 32 + kg * 8;
            f16x8 v;
            #pragma unroll
            for (int e = 0; e < 8; ++e) v[e] = (_Float16)wp[e];
            Wf[nt][kc] = v;
        }
    }
    float ho[16];
    #pragma unroll
    for (int i = 0; i < 16; ++i) ho[i] = 0.f;
    for (int i = tid; i < 2048; i += 256) ((int*)hb[0])[i] = 0;
    __syncthreads();

    for (int t = 0; t < 128; ++t) {
        int cur = t & 1, nxt = cur ^ 1;
        f32x4 acc[12];
        #pragma unroll
        for (int nt = 0; nt < 12; ++nt)
            #pragma unroll
            for (int e = 0; e < 4; ++e) acc[nt][e] = 0.f;
        #pragma unroll
        for (int kc = 0; kc < 8; ++kc) {
            int roff = (n * 512 + kc * 64 + kg * 16) ^ ((n & 7) << 4);
            f16x8 a = *(const f16x8*)(hb[cur] + roff);
            #pragma unroll
            for (int nt = 0; nt < 12; ++nt)
                acc[nt] = __builtin_amdgcn_mfma_f32_16x16x32_f16(a, Wf[nt][kc], acc[nt], 0, 0, 0);
        }
        #pragma unroll
        for (int q = 0; q < 4; ++q) {
            int l = w * 64 + q * 16 + n;
            #pragma unroll
            for (int r = 0; r < 4; ++r) {
                int bl = kg * 4 + r;
                size_t gib = ((size_t)t * 256 + bg0 + bl) * 768;
                float ir  = __half2float(gih[gib + l]);
                float iz  = __half2float(gih[gib + 256 + l]);
                float in_ = __half2float(gih[gib + 512 + l]);
                float rr = sigm(ir + acc[q][r] + bh[q]);
                float zz = sigm(iz + acc[4 + q][r] + bh[4 + q]);
                float nn = tanh_(in_ + rr * (acc[8 + q][r] + bh[8 + q]));
                float h = (1.f - zz) * nn + zz * ho[q * 4 + r];
                ho[q * 4 + r] = h;
                int byteoff = (bl * 512 + l * 2) ^ ((bl & 7) << 4);
                *(_Float16*)(hb[nxt] + byteoff) = (_Float16)h;
            }
        }
        __syncthreads();
    }
    #pragma unroll
    for (int q = 0; q < 4; ++q) {
        int l = w * 64 + q * 16 + n;
        #pragma unroll
        for (int r = 0; r < 4; ++r) {
            int bg = bg0 + kg * 4 + r;
            float h = ho[q * 4 + r];
            cc[(size_t)bg * 256 + l] = h;
            out[2 + (size_t)bg * 256 + l] = h;
        }
    }
}

// ---------------- pred: pred[k][c][m] = cc[c]·pred_W[k][m] + pred_b[k][m] ----------------
__global__ void pred_kernel(const float* __restrict__ cc, const float* __restrict__ pW,
                            const float* __restrict__ pb, float* __restrict__ pred,
                            __half* __restrict__ predh) {
    __shared__ float ccs[16][256];
    int tid = threadIdx.x;
    int cb = blockIdx.x;   // 0..15
    int k  = blockIdx.y;   // 0..11
    int c0 = cb * 16;
    for (int i = tid; i < 16 * 256; i += 256) {
        int cl = i >> 8, l = i & 255;
        ccs[cl][l] = cc[(size_t)(c0 + cl) * 256 + l];
    }
    __syncthreads();
    int m = tid;
    const float4* wrow = (const float4*)(pW + ((size_t)k * 256 + m) * 256);
    float acc[16];
    #pragma unroll
    for (int i = 0; i < 16; ++i) acc[i] = 0.f;
    for (int l4 = 0; l4 < 64; ++l4) {
        float4 wv = wrow[l4];
        #pragma unroll
        for (int cl = 0; cl < 16; ++cl) {
            float4 cv = ((const float4*)ccs[cl])[l4];
            acc[cl] += wv.x * cv.x + wv.y * cv.y + wv.z * cv.z + wv.w * cv.w;
        }
    }
    float bias = pb[k * 256 + m];
    #pragma unroll
    for (int cl = 0; cl < 16; ++cl) {
        float v = acc[cl] + bias;
        size_t idx = ((size_t)k * 256 + c0 + cl) * 256 + m;
        pred[idx] = v;
        predh[idx] = __float2half(v);
    }
}

// ---------------- sim GEMM + fused online softmax partials ----------------
__global__ void sim_gemm(const __half* __restrict__ A, const __half* __restrict__ P,
                         float* __restrict__ pmax, float* __restrict__ psum,
                         int* __restrict__ pidx) {
    int tid = threadIdx.x;
    int lane = tid & 63, wid = tid >> 6;
    int wm = wid >> 1, wn = wid & 1;
    int mt = blockIdx.x, ct = blockIdx.y, k = blockIdx.z;
    int m0 = mt * 128 + wm * 64;
    int c0 = ct * 128 + wn * 64;
    const __half* Bw = P + (size_t)k * 65536;
    int lr = lane & 15, kg = lane >> 4;
    f32x4 acc[4][4];   // [mi][ci]
    #pragma unroll
    for (int i = 0; i < 4; ++i)
        #pragma unroll
        for (int j = 0; j < 4; ++j)
            #pragma unroll
            for (int e = 0; e < 4; ++e) acc[i][j][e] = 0.f;
    #pragma unroll
    for (int kc = 0; kc < 8; ++kc) {
        int ko = kc * 32 + kg * 8;
        f16x8 a[4], bb[4];
        #pragma unroll
        for (int mi = 0; mi < 4; ++mi)
            a[mi] = *(const f16x8*)(A + (size_t)(m0 + mi * 16 + lr) * 256 + ko);
        #pragma unroll
        for (int ci = 0; ci < 4; ++ci)
            bb[ci] = *(const f16x8*)(Bw + (size_t)(c0 + ci * 16 + lr) * 256 + ko);
        #pragma unroll
        for (int mi = 0; mi < 4; ++mi)
            #pragma unroll
            for (int ci = 0; ci < 4; ++ci)
                acc[mi][ci] = __builtin_amdgcn_mfma_f32_16x16x32_f16(a[mi], bb[ci], acc[mi][ci], 0, 0, 0);
    }
    // per-column online (max, argmax, sumexp) over this wave's 64 rows
    #pragma unroll
    for (int ci = 0; ci < 4; ++ci) {
        float vmax = -3.0e38f; int vidx = 0;
        #pragma unroll
        for (int mi = 0; mi < 4; ++mi)
            #pragma unroll
            for (int r = 0; r < 4; ++r) {
                float v = acc[mi][ci][r];
                if (v > vmax) { vmax = v; vidx = m0 + mi * 16 + kg * 4 + r; }
            }
        float se = 0.f;
        #pragma unroll
        for (int mi = 0; mi < 4; ++mi)
            #pragma unroll
            for (int r = 0; r < 4; ++r)
                se += __expf(acc[mi][ci][r] - vmax);
        {   // combine across lanes xor 16
            float om = __shfl_xor(vmax, 16); float os = __shfl_xor(se, 16); int oi = __shfl_xor(vidx, 16);
            float nm = fmaxf(vmax, om);
            se = se * __expf(vmax - nm) + os * __expf(om - nm);
            if (om > vmax || (om == vmax && oi < vidx)) vidx = oi;
            vmax = nm;
        }
        {   // combine across lanes xor 32
            float om = __shfl_xor(vmax, 32); float os = __shfl_xor(se, 32); int oi = __shfl_xor(vidx, 32);
            float nm = fmaxf(vmax, om);
            se = se * __expf(vmax - nm) + os * __expf(om - nm);
            if (om > vmax || (om == vmax && oi < vidx)) vidx = oi;
            vmax = nm;
        }
        if (kg == 0) {
            int c = c0 + ci * 16 + lr;
            size_t base = ((size_t)(k * 560 + mt * 2 + wm)) * 256 + c;
            pmax[base] = vmax; psum[base] = se; pidx[base] = vidx;
        }
    }
}

// ---------------- finalize: combine partials, diag, loss + accuracy ----------------
__global__ void fin_kernel(const float* __restrict__ pmax, const float* __restrict__ psum,
                           const int* __restrict__ pidx, const __half* __restrict__ ehi,
                           const __half* __restrict__ elo, const float* __restrict__ pred,
                           float* __restrict__ out) {
    int k = blockIdx.x, c = threadIdx.x;
    float M = -3.0e38f, S = 0.f, bval = -3.0e38f;
    int bidx = 0;
    for (int p = 0; p < 560; ++p) {
        size_t base = ((size_t)(k * 560 + p)) * 256 + c;
        float m = pmax[base], s = psum[base];
        int id = pidx[base];
        if (m > M) { S = S * __expf(M - m) + s; M = m; }
        else       { S += s * __expf(m - M); }
        if (m > bval || (m == bval && id < bidx)) { bval = m; bidx = id; }
    }
    float lse = M + __logf(S);
    const __half* eh = ehi + ((size_t)((128 + k) * 256 + c)) * 256;
    const __half* el = elo + ((size_t)((128 + k) * 256 + c)) * 256;
    const float* pr = pred + ((size_t)(k * 256 + c)) * 256;
    float d = 0.f;
    for (int l = 0; l < 256; ++l)
        d += (__half2float(eh[l]) + __half2float(el[l])) * pr[l];
    float lossp = lse - d;
    int corr = (bidx == (256 * (128 + k) + c)) ? 1 : 0;
    __shared__ float sl[256];
    __shared__ int si[256];
    sl[c] = lossp; si[c] = corr;
    __syncthreads();
    for (int sft = 128; sft > 0; sft >>= 1) {
        if (c < sft) { sl[c] += sl[c + sft]; si[c] += si[c + sft]; }
        __syncthreads();
    }
    if (c == 0) {
        atomicAdd(out + 1, sl[0] / 3072.f);
        atomicAdd(out + 0, ((float)si[0]) / 3072.f);
    }
}

extern "C" void kernel_launch(void* const* d_in, const int* in_sizes, int n_in,
                              void* d_out, int out_size, void* d_ws, size_t ws_size,
                              hipStream_t stream) {
    (void)in_sizes; (void)n_in; (void)out_size; (void)ws_size;
    const float* X   = (const float*)d_in[0];
    const float* cw  = (const float*)d_in[1];
    const float* cb  = (const float*)d_in[2];
    const float* Wih = (const float*)d_in[3];
    const float* Whh = (const float*)d_in[4];
    const float* bih = (const float*)d_in[5];
    const float* bhh = (const float*)d_in[6];
    const float* pW  = (const float*)d_in[7];
    const float* pb  = (const float*)d_in[8];
    float* out = (float*)d_out;

    char* ws = (char*)d_ws;
    size_t o = 0;
    auto alloc = [&](size_t bytes) { char* p = ws + o; o += (bytes + 255) & ~(size_t)255; return p; };
    __half* ehi   = (__half*)alloc(18350080);   // enc hi fp16: 35840*256
    __half* elo   = (__half*)alloc(18350080);   // enc lo fp16
    __half* gih   = (__half*)alloc(50331648);   // gi fp16: 32768*768
    __half* wih   = (__half*)alloc(393216);     // W_ih fp16
    float*  ccb   = (float*)alloc(262144);      // h_last fp32
    float*  pred  = (float*)alloc(3145728);     // pred fp32: 12*256*256
    __half* predh = (__half*)alloc(1572864);    // pred fp16
    float*  pmx   = (float*)alloc(6881280);     // partials: 12*560*256
    float*  psm   = (float*)alloc(6881280);
    int*    pix   = (int*)alloc(6881280);

    wprep_kernel<<<768, 256, 0, stream>>>(Wih, wih, out);
    conv_kernel<<<dim3(4, 256), 256, 0, stream>>>(X, cw, cb, ehi, elo);
    gi_gemm<<<dim3(256, 6), 256, 0, stream>>>(ehi, wih, bih, gih);
    gru_kernel<<<16, 256, 0, stream>>>(Whh, bhh, gih, ccb, out);
    pred_kernel<<<dim3(16, 12), 256, 0, stream>>>(ccb, pW, pb, pred, predh);
    sim_gemm<<<dim3(280, 2, 12), 256, 0, stream>>>(ehi, predh, pmx, psm, pix);
    fin_kernel<<<12, 256, 0, stream>>>(pmx, psm, pix, ehi, elo, pred, out);
}

// Round 5
// 1470.058 us; speedup vs baseline: 1.2772x; 1.2772x over previous
//
#include <hip/hip_runtime.h>
#include <hip/hip_fp16.h>

// Problem constants
// B=256, L=2048, C=12, LATENT=256, G=768, T_IN=128, T_OUT=12, S=140, STRIDE=4
// M_sim = 140*256 = 35840, M_gi = 128*256 = 32768

typedef __attribute__((ext_vector_type(4))) float f32x4;
typedef __attribute__((ext_vector_type(8))) _Float16 f16x8;
typedef __attribute__((ext_vector_type(4))) _Float16 f16x4;

__device__ inline float sigm(float x) {
    x = fminf(fmaxf(x, -30.f), 30.f);
    return 1.f / (1.f + __expf(-x));
}
__device__ inline float tanh_(float x) {
    x = fminf(fmaxf(x, -15.f), 15.f);
    float e = __expf(2.f * x);
    return (e - 1.f) / (e + 1.f);
}

// ---------------- prep: W_ih -> fp16, zero out[0..1] ----------------
__global__ void wprep_kernel(const float* __restrict__ Wih, __half* __restrict__ wh,
                             float* __restrict__ out) {
    int i = blockIdx.x * 256 + threadIdx.x;   // 768*256 = 196608 total
    wh[i] = __float2half(Wih[i]);
    if (i < 2) out[i] = 0.f;
}

// ---------------- conv encoder: enc[t][b][o], t<140, hi/lo fp16 ----------------
__global__ void conv_kernel(const float* __restrict__ X, const float* __restrict__ cw,
                            const float* __restrict__ cb, __half* __restrict__ ehi,
                            __half* __restrict__ elo) {
    __shared__ float wt[48 * 256];   // transposed: wt[cs*256 + o]
    __shared__ float xs[140 * 12];   // X window for this (b, t-chunk)
    int tid = threadIdx.x;
    int tc = blockIdx.x;   // 0..3, 35 t's each
    int b  = blockIdx.y;   // 0..255
    for (int i = tid; i < 48 * 256; i += 256) {
        int o = i / 48, cs = i % 48;
        wt[cs * 256 + o] = cw[i];
    }
    int xbase = (b * 2048 + tc * 140) * 12;
    for (int i = tid; i < 1680; i += 256) xs[i] = X[xbase + i];
    __syncthreads();
    int o = tid;
    float bias = cb[o];
    for (int tl = 0; tl < 35; ++tl) {
        float acc = bias;
        #pragma unroll
        for (int cs = 0; cs < 48; ++cs) {
            int c = cs >> 2, s = cs & 3;
            acc += xs[(tl * 4 + s) * 12 + c] * wt[cs * 256 + o];
        }
        int t = tc * 35 + tl;
        size_t m = (size_t)(t * 256 + b);
        __half h = __float2half(acc);
        ehi[m * 256 + o] = h;
        elo[m * 256 + o] = __float2half(acc - __half2float(h));
    }
}

// ---------------- gi GEMM: gi[m][j] = enc[m]·W_ih[j] + b_ih[j] (+ b_hh for r,z) ----------
// Output written in GRU-friendly permuted layout:
//   gi2[ ((((t*16 + bblk)*8 + w)*6 + nt)*256 + n*16 + row ]
// where j = g*256 + w*32 + q*16 + n, nt = g*2+q, b = bblk*16 + row.
__global__ void gi_gemm(const __half* __restrict__ A, const __half* __restrict__ Bw,
                        const float* __restrict__ bih, const float* __restrict__ bhh,
                        __half* __restrict__ out) {
    int tid = threadIdx.x;
    int lane = tid & 63, wid = tid >> 6;
    int wm = wid >> 1, wn = wid & 1;
    int mbase = blockIdx.x * 128 + wm * 64;
    int nbase = blockIdx.y * 128 + wn * 64;
    int lr = lane & 15, kg = lane >> 4;
    f32x4 acc[4][4];
    #pragma unroll
    for (int i = 0; i < 4; ++i)
        #pragma unroll
        for (int j = 0; j < 4; ++j)
            #pragma unroll
            for (int e = 0; e < 4; ++e) acc[i][j][e] = 0.f;
    #pragma unroll
    for (int kc = 0; kc < 8; ++kc) {
        int ko = kc * 32 + kg * 8;
        f16x8 a[4], bb[4];
        #pragma unroll
        for (int mi = 0; mi < 4; ++mi)
            a[mi] = *(const f16x8*)(A + (size_t)(mbase + mi * 16 + lr) * 256 + ko);
        #pragma unroll
        for (int ni = 0; ni < 4; ++ni)
            bb[ni] = *(const f16x8*)(Bw + (size_t)(nbase + ni * 16 + lr) * 256 + ko);
        #pragma unroll
        for (int mi = 0; mi < 4; ++mi)
            #pragma unroll
            for (int ni = 0; ni < 4; ++ni)
                acc[mi][ni] = __builtin_amdgcn_mfma_f32_16x16x32_f16(a[mi], bb[ni], acc[mi][ni], 0, 0, 0);
    }
    #pragma unroll
    for (int mi = 0; mi < 4; ++mi) {
        int mrow = mbase + mi * 16;      // multiple of 16
        int t    = mrow >> 8;
        int bblk = (mrow >> 4) & 15;
        #pragma unroll
        for (int ni = 0; ni < 4; ++ni) {
            int j0 = nbase + ni * 16;    // multiple of 16
            int g  = j0 >> 8;
            int w2 = (j0 & 255) >> 5;
            int q  = (j0 >> 4) & 1;
            int nt = g * 2 + q;
            int j  = j0 + lr;
            float bj = bih[j] + (g < 2 ? bhh[j] : 0.f);
            size_t obase = ((((size_t)t * 16 + bblk) * 8 + w2) * 6 + nt) * 256 + lr * 16 + kg * 4;
            f16x4 pv;
            #pragma unroll
            for (int r = 0; r < 4; ++r)
                pv[r] = (_Float16)(acc[mi][ni][r] + bj);
            *(f16x4*)(out + obase) = pv;
        }
    }
}

// ---------------- GRU: 16 blocks x 16 batch rows, 8 waves, W_hh fp16 in registers -------
// Wave w owns outputs j = g*256 + w*32 + q*16 + n (g in 0..2, q in 0..1): 96 per wave.
// gi prefetched one step ahead (h-independent). h exchanged via XOR-swizzled LDS fp16.
__global__ void __launch_bounds__(512, 1)
gru_kernel(const float* __restrict__ Whh, const float* __restrict__ bhh,
           const __half* __restrict__ gi2, float* __restrict__ cc,
           float* __restrict__ out) {
    __shared__ __align__(16) char hb[2][8192];   // h fp16, [b(16)][l(256)], XOR-swizzled
    int tid = threadIdx.x;
    int lane = tid & 63, w = tid >> 6;           // 8 waves
    int n = lane & 15, kg = lane >> 4;
    int bblk = blockIdx.x;

    f16x8 Wf[6][8];    // B-frags: nt = g*2+q -> j = g*256 + w*32 + q*16 + n
    #pragma unroll
    for (int nt = 0; nt < 6; ++nt) {
        int g = nt >> 1, q = nt & 1;
        int j = g * 256 + w * 32 + q * 16 + n;
        #pragma unroll
        for (int kc = 0; kc < 8; ++kc) {
            const float* wp = Whh + (size_t)j * 256 + kc * 32 + kg * 8;
            f16x8 v;
            #pragma unroll
            for (int e = 0; e < 8; ++e) v[e] = (_Float16)wp[e];
            Wf[nt][kc] = v;
        }
    }
    float bhn[2];
    #pragma unroll
    for (int q = 0; q < 2; ++q) bhn[q] = bhh[512 + w * 32 + q * 16 + n];

    float ho[8];   // h_old for (row kg*4+r, l = w*32+q*16+n), idx q*4+r
    #pragma unroll
    for (int i = 0; i < 8; ++i) ho[i] = 0.f;
    for (int i = tid; i < 2048; i += 512) ((int*)hb[0])[i] = 0;

    const __half* gp = gi2 + ((size_t)(bblk * 8 + w) * 6) * 256 + n * 16 + kg * 4;
    f16x4 gc[6], gn[6];
    #pragma unroll
    for (int nt = 0; nt < 6; ++nt) gc[nt] = *(const f16x4*)(gp + nt * 256);
    __syncthreads();

    for (int t = 0; t < 128; ++t) {
        int cur = t & 1, nxt = cur ^ 1;
        // prefetch gi for t+1 (reads 1 step past end on t=127: landing pad in ws, unused)
        const __half* gpn = gp + (size_t)(t + 1) * 196608;
        #pragma unroll
        for (int nt = 0; nt < 6; ++nt) gn[nt] = *(const f16x4*)(gpn + nt * 256);

        f32x4 acc[6];
        #pragma unroll
        for (int nt = 0; nt < 6; ++nt)
            #pragma unroll
            for (int e = 0; e < 4; ++e) acc[nt][e] = 0.f;
        #pragma unroll
        for (int kc = 0; kc < 8; ++kc) {
            int roff = (n * 512 + kc * 64 + kg * 16) ^ ((n & 7) << 4);
            f16x8 a = *(const f16x8*)(hb[cur] + roff);
            #pragma unroll
            for (int nt = 0; nt < 6; ++nt)
                acc[nt] = __builtin_amdgcn_mfma_f32_16x16x32_f16(a, Wf[nt][kc], acc[nt], 0, 0, 0);
        }
        #pragma unroll
        for (int q = 0; q < 2; ++q) {
            int l = w * 32 + q * 16 + n;
            #pragma unroll
            for (int r = 0; r < 4; ++r) {
                float ir  = (float)gc[q][r];
                float iz  = (float)gc[2 + q][r];
                float in_ = (float)gc[4 + q][r];
                float rr = sigm(ir + acc[q][r]);
                float zz = sigm(iz + acc[2 + q][r]);
                float nn = tanh_(in_ + rr * (acc[4 + q][r] + bhn[q]));
                float h = (1.f - zz) * nn + zz * ho[q * 4 + r];
                ho[q * 4 + r] = h;
                int bl = kg * 4 + r;
                int byteoff = (bl * 512 + l * 2) ^ ((bl & 7) << 4);
                *(_Float16*)(hb[nxt] + byteoff) = (_Float16)h;
            }
        }
        #pragma unroll
        for (int nt = 0; nt < 6; ++nt) gc[nt] = gn[nt];
        __syncthreads();
    }
    #pragma unroll
    for (int q = 0; q < 2; ++q) {
        int l = w * 32 + q * 16 + n;
        #pragma unroll
        for (int r = 0; r < 4; ++r) {
            int bg = bblk * 16 + kg * 4 + r;
            float h = ho[q * 4 + r];
            cc[(size_t)bg * 256 + l] = h;
            out[2 + (size_t)bg * 256 + l] = h;
        }
    }
}

// ---------------- pred: pred[k][c][m] = cc[c]·pred_W[k][m] + pred_b[k][m] ----------------
__global__ void pred_kernel(const float* __restrict__ cc, const float* __restrict__ pW,
                            const float* __restrict__ pb, float* __restrict__ pred,
                            __half* __restrict__ predh) {
    __shared__ float ccs[16][256];
    int tid = threadIdx.x;
    int cb = blockIdx.x;   // 0..15
    int k  = blockIdx.y;   // 0..11
    int c0 = cb * 16;
    for (int i = tid; i < 16 * 256; i += 256) {
        int cl = i >> 8, l = i & 255;
        ccs[cl][l] = cc[(size_t)(c0 + cl) * 256 + l];
    }
    __syncthreads();
    int m = tid;
    const float4* wrow = (const float4*)(pW + ((size_t)k * 256 + m) * 256);
    float acc[16];
    #pragma unroll
    for (int i = 0; i < 16; ++i) acc[i] = 0.f;
    for (int l4 = 0; l4 < 64; ++l4) {
        float4 wv = wrow[l4];
        #pragma unroll
        for (int cl = 0; cl < 16; ++cl) {
            float4 cv = ((const float4*)ccs[cl])[l4];
            acc[cl] += wv.x * cv.x + wv.y * cv.y + wv.z * cv.z + wv.w * cv.w;
        }
    }
    float bias = pb[k * 256 + m];
    #pragma unroll
    for (int cl = 0; cl < 16; ++cl) {
        float v = acc[cl] + bias;
        size_t idx = ((size_t)k * 256 + c0 + cl) * 256 + m;
        pred[idx] = v;
        predh[idx] = __float2half(v);
    }
}

// ---------------- sim GEMM + fused online softmax partials ----------------
__global__ void sim_gemm(const __half* __restrict__ A, const __half* __restrict__ P,
                         float* __restrict__ pmax, float* __restrict__ psum,
                         int* __restrict__ pidx) {
    int tid = threadIdx.x;
    int lane = tid & 63, wid = tid >> 6;
    int wm = wid >> 1, wn = wid & 1;
    int mt = blockIdx.x, ct = blockIdx.y, k = blockIdx.z;
    int m0 = mt * 128 + wm * 64;
    int c0 = ct * 128 + wn * 64;
    const __half* Bw = P + (size_t)k * 65536;
    int lr = lane & 15, kg = lane >> 4;
    f32x4 acc[4][4];   // [mi][ci]
    #pragma unroll
    for (int i = 0; i < 4; ++i)
        #pragma unroll
        for (int j = 0; j < 4; ++j)
            #pragma unroll
            for (int e = 0; e < 4; ++e) acc[i][j][e] = 0.f;
    #pragma unroll
    for (int kc = 0; kc < 8; ++kc) {
        int ko = kc * 32 + kg * 8;
        f16x8 a[4], bb[4];
        #pragma unroll
        for (int mi = 0; mi < 4; ++mi)
            a[mi] = *(const f16x8*)(A + (size_t)(m0 + mi * 16 + lr) * 256 + ko);
        #pragma unroll
        for (int ci = 0; ci < 4; ++ci)
            bb[ci] = *(const f16x8*)(Bw + (size_t)(c0 + ci * 16 + lr) * 256 + ko);
        #pragma unroll
        for (int mi = 0; mi < 4; ++mi)
            #pragma unroll
            for (int ci = 0; ci < 4; ++ci)
                acc[mi][ci] = __builtin_amdgcn_mfma_f32_16x16x32_f16(a[mi], bb[ci], acc[mi][ci], 0, 0, 0);
    }
    // per-column online (max, argmax, sumexp) over this wave's 64 rows
    #pragma unroll
    for (int ci = 0; ci < 4; ++ci) {
        float vmax = -3.0e38f; int vidx = 0;
        #pragma unroll
        for (int mi = 0; mi < 4; ++mi)
            #pragma unroll
            for (int r = 0; r < 4; ++r) {
                float v = acc[mi][ci][r];
                if (v > vmax) { vmax = v; vidx = m0 + mi * 16 + kg * 4 + r; }
            }
        float se = 0.f;
        #pragma unroll
        for (int mi = 0; mi < 4; ++mi)
            #pragma unroll
            for (int r = 0; r < 4; ++r)
                se += __expf(acc[mi][ci][r] - vmax);
        {   // combine across lanes xor 16
            float om = __shfl_xor(vmax, 16); float os = __shfl_xor(se, 16); int oi = __shfl_xor(vidx, 16);
            float nm = fmaxf(vmax, om);
            se = se * __expf(vmax - nm) + os * __expf(om - nm);
            if (om > vmax || (om == vmax && oi < vidx)) vidx = oi;
            vmax = nm;
        }
        {   // combine across lanes xor 32
            float om = __shfl_xor(vmax, 32); float os = __shfl_xor(se, 32); int oi = __shfl_xor(vidx, 32);
            float nm = fmaxf(vmax, om);
            se = se * __expf(vmax - nm) + os * __expf(om - nm);
            if (om > vmax || (om == vmax && oi < vidx)) vidx = oi;
            vmax = nm;
        }
        if (kg == 0) {
            int c = c0 + ci * 16 + lr;
            size_t base = ((size_t)(k * 560 + mt * 2 + wm)) * 256 + c;
            pmax[base] = vmax; psum[base] = se; pidx[base] = vidx;
        }
    }
}

// ---------------- finalize: combine partials, diag, loss + accuracy ----------------
__global__ void fin_kernel(const float* __restrict__ pmax, const float* __restrict__ psum,
                           const int* __restrict__ pidx, const __half* __restrict__ ehi,
                           const __half* __restrict__ elo, const float* __restrict__ pred,
                           float* __restrict__ out) {
    int k = blockIdx.x, c = threadIdx.x;
    float M = -3.0e38f, S = 0.f, bval = -3.0e38f;
    int bidx = 0;
    for (int p = 0; p < 560; ++p) {
        size_t base = ((size_t)(k * 560 + p)) * 256 + c;
        float m = pmax[base], s = psum[base];
        int id = pidx[base];
        if (m > M) { S = S * __expf(M - m) + s; M = m; }
        else       { S += s * __expf(m - M); }
        if (m > bval || (m == bval && id < bidx)) { bval = m; bidx = id; }
    }
    float lse = M + __logf(S);
    const __half* eh = ehi + ((size_t)((128 + k) * 256 + c)) * 256;
    const __half* el = elo + ((size_t)((128 + k) * 256 + c)) * 256;
    const float* pr = pred + ((size_t)(k * 256 + c)) * 256;
    float d = 0.f;
    for (int l = 0; l < 256; ++l)
        d += (__half2float(eh[l]) + __half2float(el[l])) * pr[l];
    float lossp = lse - d;
    int corr = (bidx == (256 * (128 + k) + c)) ? 1 : 0;
    __shared__ float sl[256];
    __shared__ int si[256];
    sl[c] = lossp; si[c] = corr;
    __syncthreads();
    for (int sft = 128; sft > 0; sft >>= 1) {
        if (c < sft) { sl[c] += sl[c + sft]; si[c] += si[c + sft]; }
        __syncthreads();
    }
    if (c == 0) {
        atomicAdd(out + 1, sl[0] / 3072.f);
        atomicAdd(out + 0, ((float)si[0]) / 3072.f);
    }
}

extern "C" void kernel_launch(void* const* d_in, const int* in_sizes, int n_in,
                              void* d_out, int out_size, void* d_ws, size_t ws_size,
                              hipStream_t stream) {
    (void)in_sizes; (void)n_in; (void)out_size; (void)ws_size;
    const float* X   = (const float*)d_in[0];
    const float* cw  = (const float*)d_in[1];
    const float* cb  = (const float*)d_in[2];
    const float* Wih = (const float*)d_in[3];
    const float* Whh = (const float*)d_in[4];
    const float* bih = (const float*)d_in[5];
    const float* bhh = (const float*)d_in[6];
    const float* pW  = (const float*)d_in[7];
    const float* pb  = (const float*)d_in[8];
    float* out = (float*)d_out;

    char* ws = (char*)d_ws;
    size_t o = 0;
    auto alloc = [&](size_t bytes) { char* p = ws + o; o += (bytes + 255) & ~(size_t)255; return p; };
    __half* ehi   = (__half*)alloc(18350080);   // enc hi fp16: 35840*256
    __half* elo   = (__half*)alloc(18350080);   // enc lo fp16
    __half* gi2   = (__half*)alloc(50331648 + 393216); // permuted gi fp16 (+1 t of prefetch slack)
    __half* wih   = (__half*)alloc(393216);     // W_ih fp16
    float*  ccb   = (float*)alloc(262144);      // h_last fp32
    float*  pred  = (float*)alloc(3145728);     // pred fp32: 12*256*256
    __half* predh = (__half*)alloc(1572864);    // pred fp16
    float*  pmx   = (float*)alloc(6881280);     // partials: 12*560*256
    float*  psm   = (float*)alloc(6881280);
    int*    pix   = (int*)alloc(6881280);

    wprep_kernel<<<768, 256, 0, stream>>>(Wih, wih, out);
    conv_kernel<<<dim3(4, 256), 256, 0, stream>>>(X, cw, cb, ehi, elo);
    gi_gemm<<<dim3(256, 6), 256, 0, stream>>>(ehi, wih, bih, bhh, gi2);
    gru_kernel<<<16, 512, 0, stream>>>(Whh, bhh, gi2, ccb, out);
    pred_kernel<<<dim3(16, 12), 256, 0, stream>>>(ccb, pW, pb, pred, predh);
    sim_gemm<<<dim3(280, 2, 12), 256, 0, stream>>>(ehi, predh, pmx, psm, pix);
    fin_kernel<<<12, 256, 0, stream>>>(pmx, psm, pix, ehi, elo, pred, out);
}